// Round 1
// baseline (74.972 us; speedup 1.0000x reference)
//
#include <hip/hip_runtime.h>

// Fused FAC (per-pixel 3x3 convolution with residual):
// out[n,c,h,w] = feat[n,c,h,w] + sum_{i,j} feat_pad[n,c,h+i,w+j] * att[n,i*3+j,h,w]
// feature: [8,64,256,256] f32, attention: [8,9,256,256] f32, out: [8,64,256,256] f32.
// Memory-bound: ideal 287 MB -> ~46 us @ 6.3 TB/s.

constexpr int N_ = 8, C_ = 64, H_ = 256, W_ = 256;
constexpr int ROWS = 4;                 // output rows per block
constexpr int CG = 4;                   // channel groups (blocks per pixel tile)
constexpr int CPG = C_ / CG;            // 16 channels per block
constexpr int HB = H_ / ROWS;           // 64 row tiles
constexpr int NWG = N_ * HB * CG;       // 2048 blocks
constexpr int NXCD = 8;

__global__ __launch_bounds__(256) void fac_kernel(
    const float* __restrict__ feat, const float* __restrict__ att,
    float* __restrict__ out) {
  // XCD-aware swizzle (NWG % 8 == 0 -> simple bijective form):
  // hardware bid round-robins XCDs; remap so each XCD owns a contiguous
  // logical chunk (adjacent h-tiles + channel groups share att tile / halo rows in L2).
  int bid = blockIdx.x;
  int lg = (bid % NXCD) * (NWG / NXCD) + bid / NXCD;

  int cg = lg % CG;
  int hb = (lg / CG) % HB;
  int n  = lg / (CG * HB);

  int tx = threadIdx.x & 63;   // lane: w4 = tx*4 (one wave spans full W row)
  int rt = threadIdx.x >> 6;   // wave id = row within tile (wave-uniform h)
  int h  = hb * ROWS + rt;
  int w4 = tx << 2;

  const size_t plane = (size_t)H_ * W_;

  // attention [N][9][H][W]: 9 taps for this pixel strip, kept in registers,
  // reused across all CPG channels.
  const float* attp = att + ((size_t)n * 9 * H_ + h) * (size_t)W_ + w4;
  float4 a[9];
#pragma unroll
  for (int t = 0; t < 9; ++t)
    a[t] = *(const float4*)(attp + (size_t)t * plane);

  const float* fbase =
      feat + ((size_t)n * C_ + (size_t)cg * CPG) * plane + (size_t)h * W_ + w4;
  float* obase =
      out + ((size_t)n * C_ + (size_t)cg * CPG) * plane + (size_t)h * W_ + w4;

  const bool hasUp = (h > 0);        // wave-uniform
  const bool hasDn = (h < H_ - 1);   // wave-uniform

  const float4 fzero = {0.f, 0.f, 0.f, 0.f};

  auto loadrows = [&](int c, float4& r0, float4& r1, float4& r2) {
    const float* p = fbase + (size_t)c * plane;
    r1 = *(const float4*)p;
    r0 = hasUp ? *(const float4*)(p - W_) : fzero;
    r2 = hasDn ? *(const float4*)(p + W_) : fzero;
  };

  // One input row's contribution to the 4 outputs this thread owns.
  // f = feature row at w4..w4+3; halo via wave shuffle (wave spans whole row,
  // so lane 0 / lane 63 edges are the true image edges -> zero pad).
  auto accum_row = [&](const float4& f, const float4& aL, const float4& aC,
                       const float4& aR, float4& acc) {
    float lw = __shfl_up(f.w, 1);    // f[w4-1] from lane-1
    float rx = __shfl_down(f.x, 1);  // f[w4+4] from lane+1
    if (tx == 0) lw = 0.f;
    if (tx == 63) rx = 0.f;
    acc.x += lw  * aL.x + f.x * aC.x + f.y * aR.x;
    acc.y += f.x * aL.y + f.y * aC.y + f.z * aR.y;
    acc.z += f.y * aL.z + f.z * aC.z + f.w * aR.z;
    acc.w += f.z * aL.w + f.w * aC.w + rx  * aR.w;
  };

  float4 p0, p1, p2, q0, q1, q2;
  loadrows(0, p0, p1, p2);

#pragma unroll 2
  for (int c = 0; c < CPG; ++c) {
    int cn = (c + 1 < CPG) ? (c + 1) : c;   // prefetch next channel's rows
    loadrows(cn, q0, q1, q2);

    float4 acc = p1;                        // residual: out = feat + FAC
    accum_row(p0, a[0], a[1], a[2], acc);   // row h-1, taps j=0,1,2
    accum_row(p1, a[3], a[4], a[5], acc);   // row h
    accum_row(p2, a[6], a[7], a[8], acc);   // row h+1

    *(float4*)(obase + (size_t)c * plane) = acc;

    p0 = q0; p1 = q1; p2 = q2;
  }
}

extern "C" void kernel_launch(void* const* d_in, const int* in_sizes, int n_in,
                              void* d_out, int out_size, void* d_ws, size_t ws_size,
                              hipStream_t stream) {
  const float* feat = (const float*)d_in[0];
  const float* att  = (const float*)d_in[1];
  float* out        = (float*)d_out;
  fac_kernel<<<NWG, 256, 0, stream>>>(feat, att, out);
}

// Round 3
// 72.493 us; speedup vs baseline: 1.0342x; 1.0342x over previous
//
#include <hip/hip_runtime.h>

// Fused FAC (per-pixel 3x3 convolution with residual):
// out[n,c,h,w] = feat[n,c,h,w] + sum_{i,j} feat_pad[n,c,h+i,w+j] * att[n,i*3+j,h,w]
// feature: [8,64,256,256] f32, attention: [8,9,256,256] f32, out: [8,64,256,256] f32.
// Memory-bound: ideal ~287 MB -> ~46 us @ 6.3 TB/s.
//
// Round-2: round-1 ran at 75us, latency-bound (VALUBusy 13%, HBM 37%, VGPR=48
// => compiler rematerialized the 36-VGPR attention tile inside the loop).
// Fix: __launch_bounds__(256,4) for a 128-VGPR budget, explicit depth-2
// pipeline (loads 2 channels ahead, halo shuffles 1 ahead, static ring
// indices via full unroll), nontemporal stores to keep L3 for the inputs.
// Round-3: nontemporal store needs a native clang vector type, not
// HIP_vector_type -- bitcast float4 -> ext_vector_type(4) for the store.

constexpr int N_ = 8, C_ = 64, H_ = 256, W_ = 256;
constexpr int ROWS = 4;                 // output rows per block (1 per wave)
constexpr int CG = 4;                   // channel groups (blocks per pixel tile)
constexpr int CPG = C_ / CG;            // 16 channels per block
constexpr int HB = H_ / ROWS;           // 64 row tiles
constexpr int NWG = N_ * HB * CG;       // 2048 blocks
constexpr int NXCD = 8;

using f32x4 = __attribute__((ext_vector_type(4))) float;

__global__ __launch_bounds__(256, 4) void fac_kernel(
    const float* __restrict__ feat, const float* __restrict__ att,
    float* __restrict__ out) {
  // XCD-aware bijective swizzle (NWG % 8 == 0): each XCD owns a contiguous
  // logical chunk (adjacent h-tiles/channel groups share att + halo rows in L2).
  int bid = blockIdx.x;
  int lg = (bid % NXCD) * (NWG / NXCD) + bid / NXCD;

  int cg = lg % CG;
  int hb = (lg / CG) % HB;
  int n  = lg / (CG * HB);

  int tx = threadIdx.x & 63;   // lane: w4 = tx*4 (one wave spans full W row)
  int rt = threadIdx.x >> 6;   // wave id = row within tile (wave-uniform h)
  int h  = hb * ROWS + rt;
  int w4 = tx << 2;

  const size_t plane = (size_t)H_ * W_;

  // attention [N][9][H][W]: 9 taps for this pixel strip, kept in registers,
  // reused across all CPG channels (36 VGPRs -- the whole point of the
  // 128-VGPR budget).
  const float* attp = att + ((size_t)n * 9 * H_ + h) * (size_t)W_ + w4;
  float4 a[9];
#pragma unroll
  for (int t = 0; t < 9; ++t)
    a[t] = *(const float4*)(attp + (size_t)t * plane);

  const float* fbase =
      feat + ((size_t)n * C_ + (size_t)cg * CPG) * plane + (size_t)h * W_ + w4;
  float* obase =
      out + ((size_t)n * C_ + (size_t)cg * CPG) * plane + (size_t)h * W_ + w4;

  const bool hasUp = (h > 0);        // wave-uniform
  const bool hasDn = (h < H_ - 1);   // wave-uniform
  const float4 fzero = {0.f, 0.f, 0.f, 0.f};

  // Ring buffers. ALL indices become compile-time constants after the full
  // unroll below (rule: runtime-indexed vector arrays go to scratch).
  float4 r0[3], r1[3], r2[3];              // 3 feature rows, 3 channels deep
  float lw0[2], lw1[2], lw2[2];            // w-1 halos, 2 deep
  float rx0[2], rx1[2], rx2[2];            // w+4 halos, 2 deep

  auto issue = [&](int c, int s) {         // issue 3 row loads for channel c
    const float* p = fbase + (size_t)c * plane;
    r1[s] = *(const float4*)p;
    r0[s] = hasUp ? *(const float4*)(p - W_) : fzero;
    r2[s] = hasDn ? *(const float4*)(p + W_) : fzero;
  };

  auto halos = [&](int s, int d) {         // cross-lane halos for slot s
    float v;
    v = __shfl_up(r0[s].w, 1);   lw0[d] = (tx == 0)  ? 0.f : v;
    v = __shfl_up(r1[s].w, 1);   lw1[d] = (tx == 0)  ? 0.f : v;
    v = __shfl_up(r2[s].w, 1);   lw2[d] = (tx == 0)  ? 0.f : v;
    v = __shfl_down(r0[s].x, 1); rx0[d] = (tx == 63) ? 0.f : v;
    v = __shfl_down(r1[s].x, 1); rx1[d] = (tx == 63) ? 0.f : v;
    v = __shfl_down(r2[s].x, 1); rx2[d] = (tx == 63) ? 0.f : v;
  };

  auto accum = [&](const float4& f, float lw, float rx, const float4& aL,
                   const float4& aC, const float4& aR, float4& acc) {
    acc.x += lw  * aL.x + f.x * aC.x + f.y * aR.x;
    acc.y += f.x * aL.y + f.y * aC.y + f.z * aR.y;
    acc.z += f.y * aL.z + f.z * aC.z + f.w * aR.z;
    acc.w += f.z * aL.w + f.w * aC.w + rx  * aR.w;
  };

  // Prologue: 2 channels of loads in flight, halos ready for channel 0.
  issue(0, 0);
  issue(1, 1);
  halos(0, 0);

#pragma unroll
  for (int c = 0; c < CPG; ++c) {
    const int s  = c % 3;
    const int s1 = (c + 1) % 3;
    const int s2 = (c + 2) % 3;
    const int hp = c & 1;
    const int hn = (c + 1) & 1;

    if (c + 2 < CPG) issue(c + 2, s2);     // loads: 2 iterations ahead
    if (c + 1 < CPG) halos(s1, hn);        // shuffles: 1 iteration ahead

    float4 acc = r1[s];                    // residual: out = feat + FAC
    accum(r0[s], lw0[hp], rx0[hp], a[0], a[1], a[2], acc);  // row h-1
    accum(r1[s], lw1[hp], rx1[hp], a[3], a[4], a[5], acc);  // row h
    accum(r2[s], lw2[hp], rx2[hp], a[6], a[7], a[8], acc);  // row h+1

    // Output is never re-read: keep it out of L2/L3 so inputs stay cached.
    f32x4 accv;
    accv.x = acc.x; accv.y = acc.y; accv.z = acc.z; accv.w = acc.w;
    __builtin_nontemporal_store(accv, (f32x4*)(obase + (size_t)c * plane));
  }
}

extern "C" void kernel_launch(void* const* d_in, const int* in_sizes, int n_in,
                              void* d_out, int out_size, void* d_ws, size_t ws_size,
                              hipStream_t stream) {
  const float* feat = (const float*)d_in[0];
  const float* att  = (const float*)d_in[1];
  float* out        = (float*)d_out;
  fac_kernel<<<NWG, 256, 0, stream>>>(feat, att, out);
}

// Round 4
// 47.971 us; speedup vs baseline: 1.5629x; 1.5112x over previous
//
#include <hip/hip_runtime.h>

// Fused FAC (per-pixel 3x3 convolution with residual):
// out[n,c,h,w] = feat[n,c,h,w] + sum_{i,j} feat_pad[n,c,h+i,w+j] * att[n,i*3+j,h,w]
// feature: [8,64,256,256] f32, attention: [8,9,256,256] f32, out: [8,64,256,256] f32.
//
// Round-4: rounds 1-3 were latency-bound (VALUBusy 13-15%, ~2 TB/s effective).
// Root cause: register-resident prefetch pipeline loses to the register
// allocator (VGPR stuck at 48-64; loads sunk to uses; prefetch distance ~0).
// Fix: LDS-resident pipeline via global_load_lds (no dest VGPRs -> compiler
// cannot sink it), 3-deep ring of 8-row channel tiles, raw s_barrier +
// COUNTED s_waitcnt vmcnt(N) so prefetch stays in flight across barriers.

constexpr int N_ = 8, C_ = 64, H_ = 256, W_ = 256;
constexpr int ROWS = 4;                 // output rows per block (1 per wave)
constexpr int CG = 4;                   // channel groups (blocks per pixel tile)
constexpr int CPG = C_ / CG;            // 16 channels per block
constexpr int HB = H_ / ROWS;           // 64 row tiles
constexpr int NWG = N_ * HB * CG;       // 2048 blocks
constexpr int NXCD = 8;
constexpr int NBUF = 3;                 // LDS ring depth (prefetch 2 channels ahead)
constexpr int SLOTS = 8;                // rows staged per channel (slots 0..5 used:
                                        // slot s <-> global row h0-1+s; 6,7 pad so
                                        // 8 rows = 4 waves x 2 full-row gll chunks)
constexpr int BUFF = SLOTS * W_;        // floats per ring buffer = 2048

using f32x4 = __attribute__((ext_vector_type(4))) float;

__global__ __launch_bounds__(256, 4) void fac_kernel(
    const float* __restrict__ feat, const float* __restrict__ att,
    float* __restrict__ out) {
  __shared__ float smem[NBUF * BUFF + W_];   // ring + 1 zero row (25600 B)
  constexpr int ZROW = NBUF * BUFF;

  // XCD-aware bijective swizzle (NWG % 8 == 0).
  int bid = blockIdx.x;
  int lg = (bid % NXCD) * (NWG / NXCD) + bid / NXCD;
  int cg = lg % CG;
  int hb = (lg / CG) % HB;
  int n  = lg / (CG * HB);

  int tx = threadIdx.x & 63;   // lane: w4 = tx*4 (wave spans full W row)
  int rt = threadIdx.x >> 6;   // wave id = output row within tile
  int h0 = hb * ROWS;
  int h  = h0 + rt;
  int w4 = tx << 2;

  const size_t plane = (size_t)H_ * W_;

  // Zero row: read in place of the OOB h-1 / h+1 row at image top/bottom.
  smem[ZROW + threadIdx.x] = 0.f;            // 256 threads x 4 B = 1024 B

  // Attention taps in registers, reused across all CPG channels (36 VGPRs).
  const float* attp = att + ((size_t)n * 9 * H_ + h) * (size_t)W_ + w4;
  float4 a[9];
#pragma unroll
  for (int t = 0; t < 9; ++t) a[t] = *(const float4*)(attp + (size_t)t * plane);
#pragma unroll
  for (int t = 0; t < 9; ++t)                // keep-alive: discourage remat
    asm volatile("" : "+v"(a[t].x), "+v"(a[t].y), "+v"(a[t].z), "+v"(a[t].w));

  const float* fbase = feat + ((size_t)n * C_ + (size_t)cg * CPG) * plane;
  float* obase = out + ((size_t)n * C_ + (size_t)cg * CPG) * plane
                     + (size_t)h * W_ + w4;

  // Staging: each wave fills 2 full row-slots (slot = rt*2+k). Source rows
  // clamp at image edges; clamped (wrong-row) data lands only in slots that
  // the compute phase never reads (edge waves read the zero row instead).
  const int s0 = rt * 2, s1 = s0 + 1;
  const int gr0 = min(max(h0 - 1 + s0, 0), H_ - 1);
  const int gr1 = min(max(h0 - 1 + s1, 0), H_ - 1);
  const float* src0 = fbase + (size_t)gr0 * W_ + w4;   // +lane*16B
  const float* src1 = fbase + (size_t)gr1 * W_ + w4;

  auto STAGE = [&](int ch, int buf) {
    // LDS dest is wave-uniform base + lane*16 (linear); global src is per-lane.
    __builtin_amdgcn_global_load_lds(
        (const __attribute__((address_space(1))) uint32_t*)(src0 + (size_t)ch * plane),
        (__attribute__((address_space(3))) uint32_t*)&smem[buf * BUFF + s0 * W_],
        16, 0, 0);
    __builtin_amdgcn_global_load_lds(
        (const __attribute__((address_space(1))) uint32_t*)(src1 + (size_t)ch * plane),
        (__attribute__((address_space(3))) uint32_t*)&smem[buf * BUFF + s1 * W_],
        16, 0, 0);
  };

  const bool hasUp = (h > 0);        // wave-uniform
  const bool hasDn = (h < H_ - 1);   // wave-uniform

  STAGE(0, 0);
  STAGE(1, 1);

#pragma unroll
  for (int c = 0; c < CPG; ++c) {
    // Counted waits: ensure stage(c) (all waves) is complete, but keep
    // stage(c+1) [2 ops] + last store in flight across the barrier.
    if (c == 0)
      asm volatile("s_waitcnt vmcnt(0) lgkmcnt(0)\n\ts_barrier" ::: "memory");
    else if (c == CPG - 1)
      asm volatile("s_waitcnt vmcnt(2)\n\ts_barrier" ::: "memory");
    else
      asm volatile("s_waitcnt vmcnt(3)\n\ts_barrier" ::: "memory");

    // Prefetch 2 channels ahead into the ring slot freed at iter c-1.
    if (c + 2 < CPG) STAGE(c + 2, (c + 2) % NBUF);

    const int bb = (c % NBUF) * BUFF;
    const float* rA = &smem[hasUp ? bb + rt * W_ : ZROW] + w4;        // row h-1
    const float* rB = &smem[bb + (rt + 1) * W_] + w4;                 // row h
    const float* rC = &smem[hasDn ? bb + (rt + 2) * W_ : ZROW] + w4;  // row h+1

    float4 f0 = *(const float4*)rA;
    float4 f1 = *(const float4*)rB;
    float4 f2 = *(const float4*)rC;

    // w-halos via wave shuffles (wave spans the full row; lane edges = image edges)
    float l0 = __shfl_up(f0.w, 1),  l1 = __shfl_up(f1.w, 1),  l2 = __shfl_up(f2.w, 1);
    float r0 = __shfl_down(f0.x, 1), r1 = __shfl_down(f1.x, 1), r2 = __shfl_down(f2.x, 1);
    if (tx == 0)  { l0 = 0.f; l1 = 0.f; l2 = 0.f; }
    if (tx == 63) { r0 = 0.f; r1 = 0.f; r2 = 0.f; }

    float4 acc = f1;                     // residual: out = feat + FAC
    acc.x += l0   * a[0].x + f0.x * a[1].x + f0.y * a[2].x;
    acc.y += f0.x * a[0].y + f0.y * a[1].y + f0.z * a[2].y;
    acc.z += f0.y * a[0].z + f0.z * a[1].z + f0.w * a[2].z;
    acc.w += f0.z * a[0].w + f0.w * a[1].w + r0   * a[2].w;

    acc.x += l1   * a[3].x + f1.x * a[4].x + f1.y * a[5].x;
    acc.y += f1.x * a[3].y + f1.y * a[4].y + f1.z * a[5].y;
    acc.z += f1.y * a[3].z + f1.z * a[4].z + f1.w * a[5].z;
    acc.w += f1.z * a[3].w + f1.w * a[4].w + r1   * a[5].w;

    acc.x += l2   * a[6].x + f2.x * a[7].x + f2.y * a[8].x;
    acc.y += f2.x * a[6].y + f2.y * a[7].y + f2.z * a[8].y;
    acc.z += f2.y * a[6].z + f2.z * a[7].z + f2.w * a[8].z;
    acc.w += f2.z * a[6].w + f2.w * a[7].w + r2   * a[8].w;

    // Output is never re-read: nontemporal store keeps L2/L3 for the inputs.
    f32x4 accv = {acc.x, acc.y, acc.z, acc.w};
    __builtin_nontemporal_store(accv, (f32x4*)(obase + (size_t)c * plane));
  }
}

extern "C" void kernel_launch(void* const* d_in, const int* in_sizes, int n_in,
                              void* d_out, int out_size, void* d_ws, size_t ws_size,
                              hipStream_t stream) {
  const float* feat = (const float*)d_in[0];
  const float* att  = (const float*)d_in[1];
  float* out        = (float*)d_out;
  fac_kernel<<<NWG, 256, 0, stream>>>(feat, att, out);
}